// Round 3
// baseline (8031.950 us; speedup 1.0000x reference)
//
#include <hip/hip_runtime.h>

typedef _Float16 f16;
typedef _Float16 half8 __attribute__((ext_vector_type(8)));
typedef _Float16 half4_t __attribute__((ext_vector_type(4)));
typedef float floatx4 __attribute__((ext_vector_type(4)));

#define BB 64
#define TT 512
#define II 2048
#define HH 256
#define GG 768  // 3*H

__device__ inline float sigm(float x) { return 1.0f / (1.0f + __expf(-x)); }
__device__ inline float tanh_(float x) { float t = __expf(2.0f * x); return 1.0f - 2.0f / (t + 1.0f); }

// ---------------- zero fill (16B granules) ----------------
__global__ void zero16(uint4* p, int n16) {
    int i = blockIdx.x * blockDim.x + threadIdx.x;
    if (i < n16) p[i] = make_uint4(0u, 0u, 0u, 0u);
}

// ---------------- fp32 -> fp16 convert ----------------
__global__ void cvt(const float* __restrict__ s, f16* __restrict__ d, int n) {
    int i = (blockIdx.x * blockDim.x + threadIdx.x) * 4;
    if (i + 3 < n) {
        float4 v = *(const float4*)(s + i);
        d[i + 0] = (f16)v.x; d[i + 1] = (f16)v.y; d[i + 2] = (f16)v.z; d[i + 3] = (f16)v.w;
    } else {
        for (; i < n; ++i) d[i] = (f16)s[i];
    }
}

// ---------------- build K-concat weights [w_ih | w_hh] fp16, 768 x 512 ----------------
__global__ void build_wcat(const float* __restrict__ wih, const float* __restrict__ whh,
                           f16* __restrict__ wcat) {
    int i = blockIdx.x * 256 + threadIdx.x;  // over 768*512
    int r = i >> 9, k = i & 511;
    wcat[i] = (f16)(k < 256 ? wih[r * 256 + k] : whh[r * 256 + (k - 256)]);
}

// ---------------- layer-0 input projection GEMM (fp16 out) ----------------
// out[M=32768][768] = x_remap[M][2048] @ W[768][2048]^T + bias, row r=(t,b)->x[b][t][:]
template <int K>
__global__ __launch_bounds__(256) void proj(const float* __restrict__ x,
                                            const f16* __restrict__ W,
                                            const float* __restrict__ bias,
                                            f16* __restrict__ out) {
    __shared__ f16 As[128][40];
    __shared__ f16 Bs[128][40];
    const int tid = threadIdx.x;
    const int wave = tid >> 6, lane = tid & 63, quad = lane >> 4, col = lane & 15;
    const int nt = blockIdx.x, mt = blockIdx.y;
    const int wm = wave >> 1, wn = wave & 1;

    floatx4 acc[4][4];
    const floatx4 z4 = {0.0f, 0.0f, 0.0f, 0.0f};
    for (int a = 0; a < 4; ++a)
        for (int b = 0; b < 4; ++b) acc[a][b] = z4;

    const int srow = tid >> 1;
    const int kh = tid & 1;

    for (int kt = 0; kt < K / 32; ++kt) {
        const int k0 = kt * 32;
        __syncthreads();
        {
            int r = mt * 128 + srow;
            int t = r >> 6, b = r & 63;
            const float* src = x + ((size_t)b * TT + t) * (size_t)II + k0 + kh * 16;
            for (int j = 0; j < 4; ++j) {
                float4 v = *(const float4*)(src + j * 4);
                half4_t h;
                h.x = (f16)v.x; h.y = (f16)v.y; h.z = (f16)v.z; h.w = (f16)v.w;
                *(half4_t*)&As[srow][kh * 16 + j * 4] = h;
            }
        }
        {
            const f16* src = W + (size_t)(nt * 128 + srow) * K + k0 + kh * 16;
            uint4* dst = (uint4*)&Bs[srow][kh * 16];
            dst[0] = *(const uint4*)(src);
            dst[1] = *(const uint4*)(src + 8);
        }
        __syncthreads();

        half8 af[4], bf[4];
        for (int mi = 0; mi < 4; ++mi) af[mi] = *(const half8*)&As[wm * 64 + mi * 16 + col][quad * 8];
        for (int ni = 0; ni < 4; ++ni) bf[ni] = *(const half8*)&Bs[wn * 64 + ni * 16 + col][quad * 8];
        for (int mi = 0; mi < 4; ++mi)
            for (int ni = 0; ni < 4; ++ni)
                acc[mi][ni] = __builtin_amdgcn_mfma_f32_16x16x32_f16(af[mi], bf[ni], acc[mi][ni], 0, 0, 0);
    }

    for (int mi = 0; mi < 4; ++mi)
        for (int ni = 0; ni < 4; ++ni)
            for (int r2 = 0; r2 < 4; ++r2) {
                int m = mt * 128 + wm * 64 + mi * 16 + quad * 4 + r2;
                int n = nt * 128 + wn * 64 + ni * 16 + col;
                out[(size_t)m * GG + n] = (f16)(acc[mi][ni][r2] + bias[n]);
            }
}

// ---------------- fused 3-layer pipelined GRU ----------------
// 24 WGs: layer = bx/8 (8 WGs per layer, each owns 32 h-channels).
// Layers 1/2 compute their input projection on the fly from h_{l-1}(t) (K-concat 512).
// Per-layer monotonic counter cnt[l*32]: WG adds 1 after writing its h_l(t) chunk.
//   consumer waits: own layer cnt >= 8*t (h_l(t-1) ready), upstream cnt >= 8*(t+1).
__global__ __launch_bounds__(256, 1) void gru_pipe(
    const f16* __restrict__ xg0,
    const f16* __restrict__ wcat0, const f16* __restrict__ wcat1, const f16* __restrict__ wcat2,
    const float* __restrict__ bih1, const float* __restrict__ bhh1,
    const float* __restrict__ bih2, const float* __restrict__ bhh2,
    const float* __restrict__ bhh0,
    f16* __restrict__ hs0, f16* __restrict__ hs1, f16* __restrict__ hs2,
    float* __restrict__ hfinal, unsigned* __restrict__ cnt) {
    const int tid = threadIdx.x, wave = tid >> 6, lane = tid & 63;
    const int quad = lane >> 4, col = lane & 15;
    const int l = blockIdx.x >> 3, part = blockIdx.x & 7;
    const int c0 = part * 32;
    const int mh = wave >> 1, p = wave & 1;
    const int c = c0 + p * 16 + col;  // this lane's h-channel

    const f16* wc = (l == 0) ? wcat0 : (l == 1) ? wcat1 : wcat2;
    const int K = (l == 0) ? 256 : 512;

    f16* hs_own = (l == 0) ? hs0 : (l == 1) ? hs1 : hs2;
    const f16* hs_in = (l == 1) ? hs0 : hs1;  // unused for l==0

    // register-resident B fragments: gate g, weight row g*256 + c
    half8 bfr[3][16];
#pragma unroll
    for (int g = 0; g < 3; ++g) {
        const f16* wrow = wc + (size_t)(g * 256 + c) * K;
        for (int kt = 0; kt < K / 32; ++kt)
            bfr[g][kt] = *(const half8*)(wrow + kt * 32 + quad * 8);
    }

    float br, bz, bnx, bnh;
    if (l == 0) {
        br = bhh0[c]; bz = bhh0[256 + c]; bnx = 0.0f; bnh = bhh0[512 + c];
    } else {
        const float* bi = (l == 1) ? bih1 : bih2;
        const float* bh = (l == 1) ? bhh1 : bhh2;
        br = bi[c] + bh[c]; bz = bi[256 + c] + bh[256 + c];
        bnx = bi[512 + c]; bnh = bh[512 + c];
    }

    float hreg[2][4];
#pragma unroll
    for (int a = 0; a < 2; ++a)
#pragma unroll
        for (int b = 0; b < 4; ++b) hreg[a][b] = 0.0f;

    unsigned* mycnt = cnt + l * 32;
    unsigned* incnt = cnt + (l - 1) * 32;
    const floatx4 z4 = {0.0f, 0.0f, 0.0f, 0.0f};

    for (int t = 0; t < TT; ++t) {
        if (tid == 0) {
            if (t > 0) {
                unsigned tgt = 8u * (unsigned)t;
                while (__hip_atomic_load(mycnt, __ATOMIC_ACQUIRE, __HIP_MEMORY_SCOPE_AGENT) < tgt)
                    __builtin_amdgcn_s_sleep(1);
            }
            if (l > 0) {
                unsigned tgt = 8u * (unsigned)(t + 1);
                while (__hip_atomic_load(incnt, __ATOMIC_ACQUIRE, __HIP_MEMORY_SCOPE_AGENT) < tgt)
                    __builtin_amdgcn_s_sleep(1);
            }
        }
        __syncthreads();

        // layer-0 xg prefetch (independent of h -> issue before MFMA chain)
        float xr[2][4], xz[2][4], xn[2][4];
        if (l == 0) {
#pragma unroll
            for (int mt2 = 0; mt2 < 2; ++mt2)
#pragma unroll
                for (int r2 = 0; r2 < 4; ++r2) {
                    int b = mh * 32 + mt2 * 16 + quad * 4 + r2;
                    const f16* q = xg0 + ((size_t)t * BB + b) * GG + c;
                    xr[mt2][r2] = (float)q[0];
                    xz[mt2][r2] = (float)q[256];
                    xn[mt2][r2] = (float)q[512];
                }
        }

        const f16* aH = hs_own + (size_t)t * (BB * HH);         // h_l(t-1)
        const f16* aX = hs_in + (size_t)(t + 1) * (BB * HH);    // h_{l-1}(t), l>0

        floatx4 acc_r[2], acc_z[2], acc_nx[2], acc_nh[2];
#pragma unroll
        for (int mt2 = 0; mt2 < 2; ++mt2) {
            acc_r[mt2] = z4; acc_z[mt2] = z4; acc_nx[mt2] = z4; acc_nh[mt2] = z4;
        }

#pragma unroll
        for (int mt2 = 0; mt2 < 2; ++mt2) {
            const int m = mh * 32 + mt2 * 16 + col;
            half8 af[16];
            if (l == 0) {
#pragma unroll
                for (int kt = 0; kt < 8; ++kt)
                    af[kt] = *(const half8*)(aH + (size_t)m * HH + kt * 32 + quad * 8);
#pragma unroll
                for (int kt = 0; kt < 8; ++kt) {
                    acc_r[mt2] = __builtin_amdgcn_mfma_f32_16x16x32_f16(af[kt], bfr[0][kt], acc_r[mt2], 0, 0, 0);
                    acc_z[mt2] = __builtin_amdgcn_mfma_f32_16x16x32_f16(af[kt], bfr[1][kt], acc_z[mt2], 0, 0, 0);
                    acc_nh[mt2] = __builtin_amdgcn_mfma_f32_16x16x32_f16(af[kt], bfr[2][kt], acc_nh[mt2], 0, 0, 0);
                }
            } else {
#pragma unroll
                for (int kt = 0; kt < 8; ++kt)
                    af[kt] = *(const half8*)(aX + (size_t)m * HH + kt * 32 + quad * 8);
#pragma unroll
                for (int kt = 0; kt < 8; ++kt)
                    af[8 + kt] = *(const half8*)(aH + (size_t)m * HH + kt * 32 + quad * 8);
#pragma unroll
                for (int kt = 0; kt < 8; ++kt) {
                    acc_r[mt2] = __builtin_amdgcn_mfma_f32_16x16x32_f16(af[kt], bfr[0][kt], acc_r[mt2], 0, 0, 0);
                    acc_z[mt2] = __builtin_amdgcn_mfma_f32_16x16x32_f16(af[kt], bfr[1][kt], acc_z[mt2], 0, 0, 0);
                    acc_nx[mt2] = __builtin_amdgcn_mfma_f32_16x16x32_f16(af[kt], bfr[2][kt], acc_nx[mt2], 0, 0, 0);
                }
#pragma unroll
                for (int kt = 8; kt < 16; ++kt) {
                    acc_r[mt2] = __builtin_amdgcn_mfma_f32_16x16x32_f16(af[kt], bfr[0][kt], acc_r[mt2], 0, 0, 0);
                    acc_z[mt2] = __builtin_amdgcn_mfma_f32_16x16x32_f16(af[kt], bfr[1][kt], acc_z[mt2], 0, 0, 0);
                    acc_nh[mt2] = __builtin_amdgcn_mfma_f32_16x16x32_f16(af[kt], bfr[2][kt], acc_nh[mt2], 0, 0, 0);
                }
            }
        }

        f16* hso = hs_own + (size_t)(t + 1) * (BB * HH);
#pragma unroll
        for (int mt2 = 0; mt2 < 2; ++mt2)
#pragma unroll
            for (int r2 = 0; r2 < 4; ++r2) {
                int b = mh * 32 + mt2 * 16 + quad * 4 + r2;
                float rv, zv, nv;
                if (l == 0) {
                    rv = sigm(xr[mt2][r2] + acc_r[mt2][r2] + br);
                    zv = sigm(xz[mt2][r2] + acc_z[mt2][r2] + bz);
                    nv = tanh_(xn[mt2][r2] + rv * (acc_nh[mt2][r2] + bnh));
                } else {
                    rv = sigm(acc_r[mt2][r2] + br);
                    zv = sigm(acc_z[mt2][r2] + bz);
                    nv = tanh_(acc_nx[mt2][r2] + bnx + rv * (acc_nh[mt2][r2] + bnh));
                }
                float h = (1.0f - zv) * nv + zv * hreg[mt2][r2];
                hreg[mt2][r2] = h;
                hso[(size_t)b * HH + c] = (f16)h;
                if (l == 2 && t == TT - 1) hfinal[(size_t)b * HH + c] = h;
            }

        __syncthreads();  // all WG stores issued & drained before release
        if (tid == 0)
            __hip_atomic_fetch_add(mycnt, 1u, __ATOMIC_RELEASE, __HIP_MEMORY_SCOPE_AGENT);
    }
}

// ---------------- fused head: relu(h@fc1^T+b1) @ fco^T + b2 ----------------
__global__ __launch_bounds__(128) void fc_head(const float* __restrict__ h,
                                               const float* __restrict__ w1,
                                               const float* __restrict__ b1,
                                               const float* __restrict__ w2,
                                               const float* __restrict__ b2,
                                               float* __restrict__ out) {
    int b = blockIdx.x, f = threadIdx.x;
    const float* hb = h + b * HH;
    const float* wr = w1 + (size_t)f * HH;
    float a = b1[f];
    for (int c = 0; c < HH; c += 4) {
        float4 wv = *(const float4*)(wr + c);
        float4 hv = *(const float4*)(hb + c);
        a += wv.x * hv.x + wv.y * hv.y + wv.z * hv.z + wv.w * hv.w;
    }
    float z = fmaxf(a, 0.0f) * w2[f];
    for (int off = 32; off; off >>= 1) z += __shfl_down(z, off, 64);
    __shared__ float red[2];
    if ((f & 63) == 0) red[f >> 6] = z;
    __syncthreads();
    if (f == 0) out[b] = red[0] + red[1] + b2[0];
}

extern "C" void kernel_launch(void* const* d_in, const int* in_sizes, int n_in,
                              void* d_out, int out_size, void* d_ws, size_t ws_size,
                              hipStream_t stream) {
    const float* x = (const float*)d_in[0];
    const float* wih[3] = {(const float*)d_in[1], (const float*)d_in[5], (const float*)d_in[9]};
    const float* whh[3] = {(const float*)d_in[2], (const float*)d_in[6], (const float*)d_in[10]};
    const float* bih[3] = {(const float*)d_in[3], (const float*)d_in[7], (const float*)d_in[11]};
    const float* bhh[3] = {(const float*)d_in[4], (const float*)d_in[8], (const float*)d_in[12]};
    const float* fc1w = (const float*)d_in[13];
    const float* fc1b = (const float*)d_in[14];
    const float* fcow = (const float*)d_in[15];
    const float* fcob = (const float*)d_in[16];

    char* p = (char*)d_ws;
    auto alloc = [&](size_t bytes) {
        void* r = (void*)p;
        p += (bytes + 255) & ~(size_t)255;
        return r;
    };
    f16* xg0 = (f16*)alloc((size_t)TT * BB * GG * 2);      // 50.3 MB
    f16* wih0h = (f16*)alloc((size_t)GG * II * 2);         // layer-0 input weights f16
    f16* wcat0 = (f16*)alloc((size_t)GG * HH * 2);         // layer-0: w_hh only (K=256)
    f16* wcat1 = (f16*)alloc((size_t)GG * 512 * 2);        // [w_ih | w_hh]
    f16* wcat2 = (f16*)alloc((size_t)GG * 512 * 2);
    f16* hs[3];
    for (int l = 0; l < 3; ++l) hs[l] = (f16*)alloc((size_t)(TT + 1) * BB * HH * 2);  // 16.8 MB ea
    float* hfinal = (float*)alloc((size_t)BB * HH * 4);
    unsigned* cnt = (unsigned*)alloc(512);  // 3 counters, 128B apart

    // weight preprocessing
    {
        int n0 = GG * II;
        cvt<<<(n0 / 4 + 255) / 256, 256, 0, stream>>>(wih[0], wih0h, n0);
        int n1 = GG * HH;
        cvt<<<(n1 / 4 + 255) / 256, 256, 0, stream>>>(whh[0], wcat0, n1);
        build_wcat<<<GG * 512 / 256, 256, 0, stream>>>(wih[1], whh[1], wcat1);
        build_wcat<<<GG * 512 / 256, 256, 0, stream>>>(wih[2], whh[2], wcat2);
    }
    // zero hs slot 0 (h(-1)=0): 64*256 f16 = 2048 uint4; and counters
    for (int l = 0; l < 3; ++l) zero16<<<8, 256, 0, stream>>>((uint4*)hs[l], 2048);
    zero16<<<1, 64, 0, stream>>>((uint4*)cnt, 32);

    // layer-0 input projection (fp16 out, bias fused)
    proj<II><<<dim3(6, 256), 256, 0, stream>>>(x, wih0h, bih[0], xg0);

    // fused pipelined recurrence, all 3 layers
    gru_pipe<<<24, 256, 0, stream>>>(xg0, wcat0, wcat1, wcat2,
                                     bih[1], bhh[1], bih[2], bhh[2], bhh[0],
                                     hs[0], hs[1], hs[2], hfinal, cnt);

    fc_head<<<64, 128, 0, stream>>>(hfinal, fc1w, fc1b, fcow, fcob, (float*)d_out);
}

// Round 4
// 3345.726 us; speedup vs baseline: 2.4007x; 2.4007x over previous
//
#include <hip/hip_runtime.h>

typedef _Float16 f16;
typedef _Float16 half8 __attribute__((ext_vector_type(8)));
typedef _Float16 half4_t __attribute__((ext_vector_type(4)));
typedef float floatx4 __attribute__((ext_vector_type(4)));

#define BB 64
#define TT 512
#define II 2048
#define HH 256
#define GG 768  // 3*H

__device__ inline float sigm(float x) { return 1.0f / (1.0f + __expf(-x)); }
__device__ inline float tanh_(float x) { float t = __expf(2.0f * x); return 1.0f - 2.0f / (t + 1.0f); }

// ---------------- zero fill (16B granules) ----------------
__global__ void zero16(uint4* p, int n16) {
    int i = blockIdx.x * blockDim.x + threadIdx.x;
    if (i < n16) p[i] = make_uint4(0u, 0u, 0u, 0u);
}

// ---------------- fp32 -> fp16 convert ----------------
__global__ void cvt(const float* __restrict__ s, f16* __restrict__ d, int n) {
    int i = (blockIdx.x * blockDim.x + threadIdx.x) * 4;
    if (i + 3 < n) {
        float4 v = *(const float4*)(s + i);
        d[i + 0] = (f16)v.x; d[i + 1] = (f16)v.y; d[i + 2] = (f16)v.z; d[i + 3] = (f16)v.w;
    } else {
        for (; i < n; ++i) d[i] = (f16)s[i];
    }
}

// ---------------- build K-concat weights [w_ih | w_hh] fp16, 768 x 512 ----------------
__global__ void build_wcat(const float* __restrict__ wih, const float* __restrict__ whh,
                           f16* __restrict__ wcat) {
    int i = blockIdx.x * 256 + threadIdx.x;  // over 768*512
    int r = i >> 9, k = i & 511;
    wcat[i] = (f16)(k < 256 ? wih[r * 256 + k] : whh[r * 256 + (k - 256)]);
}

// ---------------- layer-0 input projection GEMM (fp16 out, bias fused) ----------------
template <int K>
__global__ __launch_bounds__(256) void proj(const float* __restrict__ x,
                                            const f16* __restrict__ W,
                                            const float* __restrict__ bias,
                                            f16* __restrict__ out) {
    __shared__ f16 As[128][40];
    __shared__ f16 Bs[128][40];
    const int tid = threadIdx.x;
    const int wave = tid >> 6, lane = tid & 63, quad = lane >> 4, col = lane & 15;
    const int nt = blockIdx.x, mt = blockIdx.y;
    const int wm = wave >> 1, wn = wave & 1;

    floatx4 acc[4][4];
    const floatx4 z4 = {0.0f, 0.0f, 0.0f, 0.0f};
    for (int a = 0; a < 4; ++a)
        for (int b = 0; b < 4; ++b) acc[a][b] = z4;

    const int srow = tid >> 1;
    const int kh = tid & 1;

    for (int kt = 0; kt < K / 32; ++kt) {
        const int k0 = kt * 32;
        __syncthreads();
        {
            int r = mt * 128 + srow;
            int t = r >> 6, b = r & 63;
            const float* src = x + ((size_t)b * TT + t) * (size_t)II + k0 + kh * 16;
            for (int j = 0; j < 4; ++j) {
                float4 v = *(const float4*)(src + j * 4);
                half4_t h;
                h.x = (f16)v.x; h.y = (f16)v.y; h.z = (f16)v.z; h.w = (f16)v.w;
                *(half4_t*)&As[srow][kh * 16 + j * 4] = h;
            }
        }
        {
            const f16* src = W + (size_t)(nt * 128 + srow) * K + k0 + kh * 16;
            uint4* dst = (uint4*)&Bs[srow][kh * 16];
            dst[0] = *(const uint4*)(src);
            dst[1] = *(const uint4*)(src + 8);
        }
        __syncthreads();

        half8 af[4], bf[4];
        for (int mi = 0; mi < 4; ++mi) af[mi] = *(const half8*)&As[wm * 64 + mi * 16 + col][quad * 8];
        for (int ni = 0; ni < 4; ++ni) bf[ni] = *(const half8*)&Bs[wn * 64 + ni * 16 + col][quad * 8];
        for (int mi = 0; mi < 4; ++mi)
            for (int ni = 0; ni < 4; ++ni)
                acc[mi][ni] = __builtin_amdgcn_mfma_f32_16x16x32_f16(af[mi], bf[ni], acc[mi][ni], 0, 0, 0);
    }

    for (int mi = 0; mi < 4; ++mi)
        for (int ni = 0; ni < 4; ++ni)
            for (int r2 = 0; r2 < 4; ++r2) {
                int m = mt * 128 + wm * 64 + mi * 16 + quad * 4 + r2;
                int n = nt * 128 + wn * 64 + ni * 16 + col;
                out[(size_t)m * GG + n] = (f16)(acc[mi][ni][r2] + bias[n]);
            }
}

// ---------------- fused 3-layer pipelined GRU, LDS-resident weights ----------------
// 40 WGs: l0 = WG 0..7 (32 ch each, K=256), l1 = 8..23 (16 ch, K=512), l2 = 24..39.
// Each WG stages its 48 KB weight slice in LDS once (swizzled fragment order:
// blk=(t_n*KT+kt), lane-sequential 16B -> conflict-free ds_read_b128).
// Sync: per-WG flag word (steps completed), release-store by producer; consumer
// wave-0 polls own-layer + upstream flags with acquire loads in one ballot.
#define FLSTRIDE 32  // uints between flag slots (128 B)
__global__ __launch_bounds__(256, 1) void gru_pipe(
    const f16* __restrict__ xg0,
    const f16* __restrict__ wcat0, const f16* __restrict__ wcat1, const f16* __restrict__ wcat2,
    const float* __restrict__ bih1, const float* __restrict__ bhh1,
    const float* __restrict__ bih2, const float* __restrict__ bhh2,
    const float* __restrict__ bhh0,
    f16* __restrict__ hs0, f16* __restrict__ hs1, f16* __restrict__ hs2,
    float* __restrict__ hfinal, unsigned* __restrict__ flags) {
    __shared__ f16 sw[24576];  // 48 KB
    const int tid = threadIdx.x, wave = tid >> 6, lane = tid & 63;
    const int quad = lane >> 4, col = lane & 15;

    const int bx = blockIdx.x;
    const int l = (bx < 8) ? 0 : (bx < 24) ? 1 : 2;
    const int part = (l == 0) ? bx : (l == 1) ? (bx - 8) : (bx - 24);
    const int NCH = (l == 0) ? 32 : 16;
    const int K = (l == 0) ? 256 : 512;
    const int KT = K / 32;
    const int c0 = part * NCH;
    const int nOwn = (l == 0) ? 8 : 16;
    const int nUp = (l == 1) ? 8 : 16;

    const f16* wc = (l == 0) ? wcat0 : (l == 1) ? wcat1 : wcat2;
    f16* hs_own = (l == 0) ? hs0 : (l == 1) ? hs1 : hs2;
    const f16* hs_in = (l == 1) ? hs0 : hs1;  // unused for l==0

    // ---- stage weights into LDS (once), swizzled fragment order ----
    for (int n = tid; n < 48 * 64; n += 256) {
        int blk = n >> 6, li = n & 63;
        int q = li >> 4, cc = li & 15;
        int t_n = blk / KT, kt = blk % KT;
        int g, ch;
        if (l == 0) { g = t_n >> 1; ch = c0 + ((t_n & 1) << 4) + cc; }
        else        { g = t_n;      ch = c0 + cc; }
        const f16* src = wc + (size_t)(g * 256 + ch) * K + kt * 32 + q * 8;
        *(uint4*)&sw[(size_t)blk * 512 + li * 8] = *(const uint4*)src;
    }

    // ---- biases (per lane channel) ----
    float br[2], bz[2], bnx[2], bnh[2];
    if (l == 0) {
        for (int p = 0; p < 2; ++p) {
            int c = c0 + p * 16 + col;
            br[p] = bhh0[c]; bz[p] = bhh0[256 + c]; bnx[p] = 0.0f; bnh[p] = bhh0[512 + c];
        }
    } else {
        const float* bi = (l == 1) ? bih1 : bih2;
        const float* bh = (l == 1) ? bhh1 : bhh2;
        int c = c0 + col;
        br[0] = bi[c] + bh[c]; bz[0] = bi[256 + c] + bh[256 + c];
        bnx[0] = bi[512 + c]; bnh[0] = bh[512 + c];
    }

    float hreg[2][4];
    for (int a = 0; a < 2; ++a)
        for (int b = 0; b < 4; ++b) hreg[a][b] = 0.0f;

    unsigned* ownf = flags + (size_t)l * 16 * FLSTRIDE;
    unsigned* upf = flags + (size_t)(l - 1) * 16 * FLSTRIDE;
    unsigned* myslot = ownf + (size_t)part * FLSTRIDE;

    __syncthreads();  // LDS staging complete

    const int m0 = wave * 16;  // this wave's batch rows
    const floatx4 z4 = {0.0f, 0.0f, 0.0f, 0.0f};

    for (int t = 0; t < TT; ++t) {
        // ---- acquire: own layer done step t-1 (all parts), upstream done step t ----
        if (wave == 0) {
            const bool mo = lane < nOwn;
            const bool mu = (l > 0) && lane >= 16 && lane < 16 + nUp;
            unsigned* oa = ownf + (size_t)lane * FLSTRIDE;
            unsigned* ua = upf + (size_t)(lane - 16) * FLSTRIDE;
            for (;;) {
                bool ok = true;
                if (mo) ok = __hip_atomic_load(oa, __ATOMIC_ACQUIRE, __HIP_MEMORY_SCOPE_AGENT) >= (unsigned)t;
                if (mu) ok = __hip_atomic_load(ua, __ATOMIC_ACQUIRE, __HIP_MEMORY_SCOPE_AGENT) >= (unsigned)(t + 1);
                if (__ballot(ok) == ~0ull) break;
                __builtin_amdgcn_s_sleep(1);
            }
        }
        __syncthreads();

        const f16* aH = hs_own + (size_t)t * (BB * HH);       // h_l(t-1)
        const f16* aX = hs_in + (size_t)(t + 1) * (BB * HH);  // h_{l-1}(t)

        if (l == 0) {
            // xg0 gate pre-activations for this lane's channels
            float xr[2][4], xz[2][4], xn[2][4];
#pragma unroll
            for (int p = 0; p < 2; ++p) {
                int c = c0 + p * 16 + col;
#pragma unroll
                for (int r2 = 0; r2 < 4; ++r2) {
                    int b = m0 + quad * 4 + r2;
                    const f16* q = xg0 + ((size_t)t * BB + b) * GG + c;
                    xr[p][r2] = (float)q[0]; xz[p][r2] = (float)q[256]; xn[p][r2] = (float)q[512];
                }
            }
            half8 af[8];
#pragma unroll
            for (int kt = 0; kt < 8; ++kt)
                af[kt] = *(const half8*)(aH + (size_t)(m0 + col) * HH + kt * 32 + quad * 8);

            floatx4 acc[6];
#pragma unroll
            for (int j = 0; j < 6; ++j) acc[j] = z4;
#pragma unroll
            for (int kt = 0; kt < 8; ++kt)
#pragma unroll
                for (int j = 0; j < 6; ++j) {
                    half8 bf = *(const half8*)&sw[(size_t)(j * 8 + kt) * 512 + lane * 8];
                    acc[j] = __builtin_amdgcn_mfma_f32_16x16x32_f16(af[kt], bf, acc[j], 0, 0, 0);
                }

            f16* hso = hs_own + (size_t)(t + 1) * (BB * HH);
#pragma unroll
            for (int p = 0; p < 2; ++p) {
                int c = c0 + p * 16 + col;
#pragma unroll
                for (int r2 = 0; r2 < 4; ++r2) {
                    int b = m0 + quad * 4 + r2;
                    float rv = sigm(xr[p][r2] + acc[0 * 2 + p][r2] + br[p]);
                    float zv = sigm(xz[p][r2] + acc[1 * 2 + p][r2] + bz[p]);
                    float nv = tanh_(xn[p][r2] + rv * (acc[2 * 2 + p][r2] + bnh[p]));
                    float h = (1.0f - zv) * nv + zv * hreg[p][r2];
                    hreg[p][r2] = h;
                    hso[(size_t)b * HH + c] = (f16)h;
                }
            }
        } else {
            half8 afX[8], afH[8];
#pragma unroll
            for (int kt = 0; kt < 8; ++kt)
                afX[kt] = *(const half8*)(aX + (size_t)(m0 + col) * HH + kt * 32 + quad * 8);
#pragma unroll
            for (int kt = 0; kt < 8; ++kt)
                afH[kt] = *(const half8*)(aH + (size_t)(m0 + col) * HH + kt * 32 + quad * 8);

            floatx4 acc_r = z4, acc_z = z4, acc_nx = z4, acc_nh = z4;
#pragma unroll
            for (int kt = 0; kt < 16; ++kt) {
                half8 a = (kt < 8) ? afX[kt] : afH[kt - 8];
                half8 b0 = *(const half8*)&sw[(size_t)(0 * 16 + kt) * 512 + lane * 8];
                half8 b1 = *(const half8*)&sw[(size_t)(1 * 16 + kt) * 512 + lane * 8];
                half8 b2 = *(const half8*)&sw[(size_t)(2 * 16 + kt) * 512 + lane * 8];
                acc_r = __builtin_amdgcn_mfma_f32_16x16x32_f16(a, b0, acc_r, 0, 0, 0);
                acc_z = __builtin_amdgcn_mfma_f32_16x16x32_f16(a, b1, acc_z, 0, 0, 0);
                if (kt < 8)
                    acc_nx = __builtin_amdgcn_mfma_f32_16x16x32_f16(a, b2, acc_nx, 0, 0, 0);
                else
                    acc_nh = __builtin_amdgcn_mfma_f32_16x16x32_f16(a, b2, acc_nh, 0, 0, 0);
            }

            f16* hso = hs_own + (size_t)(t + 1) * (BB * HH);
            int c = c0 + col;
#pragma unroll
            for (int r2 = 0; r2 < 4; ++r2) {
                int b = m0 + quad * 4 + r2;
                float rv = sigm(acc_r[r2] + br[0]);
                float zv = sigm(acc_z[r2] + bz[0]);
                float nv = tanh_(acc_nx[r2] + bnx[0] + rv * (acc_nh[r2] + bnh[0]));
                float h = (1.0f - zv) * nv + zv * hreg[0][r2];
                hreg[0][r2] = h;
                hso[(size_t)b * HH + c] = (f16)h;
                if (l == 2 && t == TT - 1) hfinal[(size_t)b * HH + c] = h;
            }
        }

        __syncthreads();  // all waves' stores drained (vmcnt(0) before s_barrier)
        if (tid == 0)
            __hip_atomic_store(myslot, (unsigned)(t + 1), __ATOMIC_RELEASE, __HIP_MEMORY_SCOPE_AGENT);
    }
}

// ---------------- fused head: relu(h@fc1^T+b1) @ fco^T + b2 ----------------
__global__ __launch_bounds__(128) void fc_head(const float* __restrict__ h,
                                               const float* __restrict__ w1,
                                               const float* __restrict__ b1,
                                               const float* __restrict__ w2,
                                               const float* __restrict__ b2,
                                               float* __restrict__ out) {
    int b = blockIdx.x, f = threadIdx.x;
    const float* hb = h + b * HH;
    const float* wr = w1 + (size_t)f * HH;
    float a = b1[f];
    for (int c = 0; c < HH; c += 4) {
        float4 wv = *(const float4*)(wr + c);
        float4 hv = *(const float4*)(hb + c);
        a += wv.x * hv.x + wv.y * hv.y + wv.z * hv.z + wv.w * hv.w;
    }
    float z = fmaxf(a, 0.0f) * w2[f];
    for (int off = 32; off; off >>= 1) z += __shfl_down(z, off, 64);
    __shared__ float red[2];
    if ((f & 63) == 0) red[f >> 6] = z;
    __syncthreads();
    if (f == 0) out[b] = red[0] + red[1] + b2[0];
}

extern "C" void kernel_launch(void* const* d_in, const int* in_sizes, int n_in,
                              void* d_out, int out_size, void* d_ws, size_t ws_size,
                              hipStream_t stream) {
    const float* x = (const float*)d_in[0];
    const float* wih[3] = {(const float*)d_in[1], (const float*)d_in[5], (const float*)d_in[9]};
    const float* whh[3] = {(const float*)d_in[2], (const float*)d_in[6], (const float*)d_in[10]};
    const float* bih[3] = {(const float*)d_in[3], (const float*)d_in[7], (const float*)d_in[11]};
    const float* bhh[3] = {(const float*)d_in[4], (const float*)d_in[8], (const float*)d_in[12]};
    const float* fc1w = (const float*)d_in[13];
    const float* fc1b = (const float*)d_in[14];
    const float* fcow = (const float*)d_in[15];
    const float* fcob = (const float*)d_in[16];

    char* p = (char*)d_ws;
    auto alloc = [&](size_t bytes) {
        void* r = (void*)p;
        p += (bytes + 255) & ~(size_t)255;
        return r;
    };
    f16* xg0 = (f16*)alloc((size_t)TT * BB * GG * 2);  // 50.3 MB
    f16* wih0h = (f16*)alloc((size_t)GG * II * 2);
    f16* wcat0 = (f16*)alloc((size_t)GG * HH * 2);     // layer-0: w_hh only (K=256)
    f16* wcat1 = (f16*)alloc((size_t)GG * 512 * 2);    // [w_ih | w_hh]
    f16* wcat2 = (f16*)alloc((size_t)GG * 512 * 2);
    f16* hs[3];
    for (int l = 0; l < 3; ++l) hs[l] = (f16*)alloc((size_t)(TT + 1) * BB * HH * 2);
    float* hfinal = (float*)alloc((size_t)BB * HH * 4);
    unsigned* flags = (unsigned*)alloc(3 * 16 * FLSTRIDE * 4);  // 6 KB

    // weight preprocessing
    {
        int n0 = GG * II;
        cvt<<<(n0 / 4 + 255) / 256, 256, 0, stream>>>(wih[0], wih0h, n0);
        int n1 = GG * HH;
        cvt<<<(n1 / 4 + 255) / 256, 256, 0, stream>>>(whh[0], wcat0, n1);
        build_wcat<<<GG * 512 / 256, 256, 0, stream>>>(wih[1], whh[1], wcat1);
        build_wcat<<<GG * 512 / 256, 256, 0, stream>>>(wih[2], whh[2], wcat2);
    }
    // zero hs slot 0 (h(-1)=0): 2048 uint4 each; and flags: 1536 uints = 384 uint4
    for (int l = 0; l < 3; ++l) zero16<<<8, 256, 0, stream>>>((uint4*)hs[l], 2048);
    zero16<<<2, 256, 0, stream>>>((uint4*)flags, 384);

    // layer-0 input projection (fp16 out, bias fused)
    proj<II><<<dim3(6, 256), 256, 0, stream>>>(x, wih0h, bih[0], xg0);

    // fused pipelined recurrence, all 3 layers
    gru_pipe<<<40, 256, 0, stream>>>(xg0, wcat0, wcat1, wcat2,
                                     bih[1], bhh[1], bih[2], bhh[2], bhh[0],
                                     hs[0], hs[1], hs[2], hfinal, flags);

    fc_head<<<64, 128, 0, stream>>>(hfinal, fc1w, fc1b, fcow, fcob, (float*)d_out);
}